// Round 3
// baseline (406.285 us; speedup 1.0000x reference)
//
#include <hip/hip_runtime.h>
#include <hip/hip_bf16.h>

#define IN_DIM 1024
#define OUT_DIM 1024
#define NE 8
#define NT 8192
#define KE (NE*IN_DIM)      // 8192
#define BM 128
#define BN 128
#define BK 64
#define KTE (IN_DIM/BK)     // 16 k-steps per expert

typedef unsigned short u16;
typedef __attribute__((ext_vector_type(4))) float f32x4;
typedef __attribute__((ext_vector_type(8))) short short8;

__device__ inline u16 f2bf(float f){
  unsigned u = __float_as_uint(f);
  return (u16)((u + 0x7fffu + ((u>>16)&1u)) >> 16);   // RNE
}

__device__ inline void gload16(const void* g, void* l){
  __builtin_amdgcn_global_load_lds(
    (const __attribute__((address_space(1))) void*)g,
    (__attribute__((address_space(3))) void*)l, 16, 0, 0);
}

// ---- gates = softmax(x @ Wg + bg); also writes Apad[n][c] = bf16 gate (c<8) ----
__global__ void k_gates(const float* __restrict__ x, const float* __restrict__ Wg,
                        const float* __restrict__ bg, float* __restrict__ gates,
                        u16* __restrict__ Apad){
  int lane = threadIdx.x & 63;
  int n = blockIdx.x*4 + (threadIdx.x>>6);
  const float* xr = x + (size_t)n*IN_DIM;
  float p[NE];
  #pragma unroll
  for(int e=0;e<NE;e++) p[e]=0.f;
  for(int i = lane*4; i < IN_DIM; i += 256){
    float4 xv = *(const float4*)(xr + i);
    const float* wr = Wg + (size_t)i*NE;
    #pragma unroll
    for(int j=0;j<4;j++){
      float xs = (&xv.x)[j];
      #pragma unroll
      for(int e=0;e<NE;e++) p[e] = fmaf(xs, wr[j*NE+e], p[e]);
    }
  }
  #pragma unroll
  for(int e=0;e<NE;e++){
    float v = p[e];
    #pragma unroll
    for(int off=32;off;off>>=1) v += __shfl_xor(v, off);
    p[e]=v;
  }
  float m = -1e30f;
  #pragma unroll
  for(int e=0;e<NE;e++){ p[e] += bg[e]; m = fmaxf(m, p[e]); }
  float s = 0.f;
  #pragma unroll
  for(int e=0;e<NE;e++){ p[e] = __expf(p[e]-m); s += p[e]; }
  float inv = 1.f/s;
  float gsel = p[0];
  #pragma unroll
  for (int e=1;e<NE;e++) gsel = (lane==e) ? p[e] : gsel;   // static select chain
  gsel *= inv;
  if (lane < NE) gates[(size_t)n*NE + lane] = gsel;
  Apad[(size_t)n*64 + lane] = (lane < NE) ? f2bf(gsel) : (u16)0;
}

// ---- x fp32 [8192][1024] -> xb bf16 (8 elems/thread) ----
__global__ void k_xb(const float* __restrict__ x, u16* __restrict__ xb){
  size_t base = ((size_t)blockIdx.x*256 + threadIdx.x) * 8;
  float4 v0 = *(const float4*)(x + base);
  float4 v1 = *(const float4*)(x + base + 4);
  union { u16 u[8]; short8 v; } t;
  t.u[0]=f2bf(v0.x); t.u[1]=f2bf(v0.y); t.u[2]=f2bf(v0.z); t.u[3]=f2bf(v0.w);
  t.u[4]=f2bf(v1.x); t.u[5]=f2bf(v1.y); t.u[6]=f2bf(v1.z); t.u[7]=f2bf(v1.w);
  *(short8*)(xb + base) = t.v;
}

// ---- We flat [8192 k][1024 o] fp32 -> WeT bf16 [1024 o][8192 k] ----
__global__ void k_wet(const float* __restrict__ We, u16* __restrict__ WeT){
  __shared__ float tile[64][65];
  int kb = blockIdx.x & 127;
  int ob = blockIdx.x >> 7;
  int k0 = kb*64, o0 = ob*64;
  int tr = threadIdx.x >> 4;
  int tc = (threadIdx.x & 15) * 4;
  #pragma unroll
  for (int p=0;p<4;p++){
    int r = p*16 + tr;
    float4 v = *(const float4*)(We + (size_t)(k0+r)*OUT_DIM + o0 + tc);
    tile[r][tc+0]=v.x; tile[r][tc+1]=v.y; tile[r][tc+2]=v.z; tile[r][tc+3]=v.w;
  }
  __syncthreads();
  #pragma unroll
  for (int p=0;p<4;p++){
    int r = p*16 + tr;              // o_local
    ushort4 o;
    o.x = f2bf(tile[tc+0][r]);
    o.y = f2bf(tile[tc+1][r]);
    o.z = f2bf(tile[tc+2][r]);
    o.w = f2bf(tile[tc+3][r]);
    *(ushort4*)(WeT + (size_t)(o0+r)*KE + k0 + tc) = o;
  }
}

// ---- Bpad[o][c] = bf16(be[c][o]) for c<8, else 0 ----
__global__ void k_bp(const float* __restrict__ be, u16* __restrict__ Bpad){
  int idx = blockIdx.x*256 + threadIdx.x;     // < 1024*64
  int o = idx >> 6, c = idx & 63;
  u16 v = 0;
  if (c < NE) v = f2bf(be[(size_t)c*OUT_DIM + o]);
  Bpad[(size_t)o*64 + c] = v;
}

// ---- GEMM: acc = sum_e g[n,e]*(xb_tile @ WeT[e]) + Apad@Bpad^T (bias) ----
// m97 structure: 128x128 tile, BK=64, 4 waves (64x64), global_load_lds 16B,
// XOR-swizzled LDS (linear dest + inverse-swizzled source + swizzled ds_read).
__global__ __launch_bounds__(256) void k_gemm(const u16* __restrict__ xb,
      const u16* __restrict__ WeT, const u16* __restrict__ Apad,
      const u16* __restrict__ Bpad, const float* __restrict__ gates,
      float* __restrict__ C){
  __shared__ u16 sA[BM*BK];
  __shared__ u16 sB[BN*BK];
  int tid = threadIdx.x;
  int wave = tid>>6, lane = tid&63;
  int bid = blockIdx.x;
  int swz = (bid & 7)*(gridDim.x>>3) + (bid>>3);   // 512 blocks: bn pinned per XCD
  int bn = swz >> 6;      // 0..7
  int bm = swz & 63;      // 0..63
  int wr = wave>>1, wc = wave&1;

  int r_ = tid>>3, gl = tid&7;
  const u16* pA[4]; const u16* pB[4];
  int rloc[4], skv[4];
  #pragma unroll
  for (int q=0;q<4;q++){
    int r = r_ + q*32;
    int sk = (gl ^ (r&7))<<3;       // inverse-swizzled source granule
    rloc[q] = r; skv[q] = sk;
    pA[q] = xb  + (size_t)(bm*BM + r)*IN_DIM + sk;
    pB[q] = WeT + (size_t)(bn*BN + r)*KE     + sk;
  }
  char* sAb = (char*)sA + wave*1024;
  char* sBb = (char*)sB + wave*1024;

  f32x4 acc[4][4];
  #pragma unroll
  for(int m=0;m<4;m++)
    #pragma unroll
    for(int n=0;n<4;n++)
      acc[m][n] = (f32x4){0.f,0.f,0.f,0.f};

  int rA = wr*64 + (lane&15);
  int rB = wc*64 + (lane&15);
  int krow = lane>>4;
  const float* gp = gates + (size_t)(bm*BM + wr*64 + (lane>>4)*4)*NE;

  for (int e=0; e<NE; ++e){
    f32x4 t[4][4];
    #pragma unroll
    for(int m=0;m<4;m++)
      #pragma unroll
      for(int n=0;n<4;n++)
        t[m][n] = (f32x4){0.f,0.f,0.f,0.f};

    for (int kt=0; kt<KTE; ++kt){
      __syncthreads();
      #pragma unroll
      for (int q=0;q<4;q++){
        gload16(pA[q], sAb + q*4096);
        gload16(pB[q], sBb + q*4096);
        pA[q] += BK; pB[q] += BK;   // pB walks straight through e*1024+kt*64
      }
      __syncthreads();
      #pragma unroll
      for (int kk=0; kk<BK; kk+=32){
        short8 af[4], bfr[4];
        int g0 = (kk>>3) + krow;
        #pragma unroll
        for (int m=0;m<4;m++){
          int R = rA + m*16;
          af[m] = *(const short8*)(sA + R*BK + ((g0 ^ (R&7))<<3));
        }
        #pragma unroll
        for (int n=0;n<4;n++){
          int R = rB + n*16;
          bfr[n] = *(const short8*)(sB + R*BK + ((g0 ^ (R&7))<<3));
        }
        #pragma unroll
        for (int m=0;m<4;m++)
          #pragma unroll
          for (int n=0;n<4;n++)
            t[m][n] = __builtin_amdgcn_mfma_f32_16x16x32_bf16(af[m], bfr[n], t[m][n], 0,0,0);
      }
    }
    pA[0] -= IN_DIM; pA[1] -= IN_DIM; pA[2] -= IN_DIM; pA[3] -= IN_DIM;

    // acc += g[row,e] * t   (fp32; gates are L2-resident)
    float gv[16];
    #pragma unroll
    for (int m=0;m<4;m++)
      #pragma unroll
      for (int j=0;j<4;j++)
        gv[m*4+j] = gp[(size_t)(m*16+j)*NE + e];
    #pragma unroll
    for (int m=0;m<4;m++)
      #pragma unroll
      for (int n=0;n<4;n++)
        #pragma unroll
        for (int j=0;j<4;j++)
          acc[m][n][j] = fmaf(gv[m*4+j], t[m][n][j], acc[m][n][j]);
  }

  // bias segment: K=64, unscaled, accumulate directly into acc
  __syncthreads();
  #pragma unroll
  for (int q=0;q<4;q++){
    gload16(Apad + (size_t)(bm*BM + rloc[q])*64 + skv[q], sAb + q*4096);
    gload16(Bpad + (size_t)(bn*BN + rloc[q])*64 + skv[q], sBb + q*4096);
  }
  __syncthreads();
  #pragma unroll
  for (int kk=0; kk<BK; kk+=32){
    short8 af[4], bfr[4];
    int g0 = (kk>>3) + krow;
    #pragma unroll
    for (int m=0;m<4;m++){
      int R = rA + m*16;
      af[m] = *(const short8*)(sA + R*BK + ((g0 ^ (R&7))<<3));
    }
    #pragma unroll
    for (int n=0;n<4;n++){
      int R = rB + n*16;
      bfr[n] = *(const short8*)(sB + R*BK + ((g0 ^ (R&7))<<3));
    }
    #pragma unroll
    for (int m=0;m<4;m++)
      #pragma unroll
      for (int n=0;n<4;n++)
        acc[m][n] = __builtin_amdgcn_mfma_f32_16x16x32_bf16(af[m], bfr[n], acc[m][n], 0,0,0);
  }

  // epilogue: C/D layout col=lane&15, row=(lane>>4)*4+reg
  int row0 = bm*BM + wr*64 + (lane>>4)*4;
  int col0 = bn*BN + wc*64 + (lane&15);
  #pragma unroll
  for (int m=0;m<4;m++)
    #pragma unroll
    for (int n=0;n<4;n++)
      #pragma unroll
      for (int j=0;j<4;j++)
        C[(size_t)(row0 + m*16 + j)*OUT_DIM + col0 + n*16] = acc[m][n][j];
}

extern "C" void kernel_launch(void* const* d_in, const int* in_sizes, int n_in,
                              void* d_out, int out_size, void* d_ws, size_t ws_size,
                              hipStream_t stream){
  const float* x  = (const float*)d_in[0];
  const float* We = (const float*)d_in[1];
  const float* be = (const float*)d_in[2];
  const float* Wg = (const float*)d_in[3];
  const float* bg = (const float*)d_in[4];
  float* out = (float*)d_out;
  char* ws = (char*)d_ws;
  // ws: gates f32 [8192][8] 256KB | Apad bf16 [8192][64] 1MB | Bpad bf16 [1024][64] 128KB
  //     | xb bf16 [8192][1024] 16MB | WeT bf16 [1024][8192] 16MB   (~33.5MB total)
  float* gates = (float*)ws;
  u16* Apad = (u16*)(ws + (256<<10));
  u16* Bpad = (u16*)(ws + (256<<10) + (1<<20));
  u16* xb   = (u16*)(ws + (256<<10) + (1<<20) + (128<<10));
  u16* WeT  = (u16*)(ws + (256<<10) + (1<<20) + (128<<10) + ((size_t)NT*IN_DIM*2));

  k_gates<<<NT/4, 256, 0, stream>>>(x, Wg, bg, gates, Apad);
  k_xb   <<<NT*IN_DIM/(256*8), 256, 0, stream>>>(x, xb);
  k_wet  <<<(KE/64)*(OUT_DIM/64), 256, 0, stream>>>(We, WeT);
  k_bp   <<<OUT_DIM*64/256, 256, 0, stream>>>(be, Bpad);
  k_gemm <<<(NT/BM)*(OUT_DIM/BN), 256, 0, stream>>>(xb, WeT, Apad, Bpad, gates, out);
}

// Round 4
// 307.573 us; speedup vs baseline: 1.3209x; 1.3209x over previous
//
#include <hip/hip_runtime.h>
#include <hip/hip_bf16.h>

#define IN_DIM 1024
#define OUT_DIM 1024
#define NE 8
#define NT 8192
#define KE (NE*IN_DIM)      // 8192
#define KPAD 64
#define KTOT (KE+KPAD)      // 8256
#define BM 256
#define BN 128
#define BK 64
#define NKT (KTOT/BK)       // 129

typedef unsigned short u16;
typedef __attribute__((ext_vector_type(4))) float f32x4;
typedef __attribute__((ext_vector_type(8))) short short8;

__device__ inline u16 f2bf(float f){
  unsigned u = __float_as_uint(f);
  return (u16)((u + 0x7fffu + ((u>>16)&1u)) >> 16);   // RNE
}

__device__ inline void gload16(const void* g, void* l){
  __builtin_amdgcn_global_load_lds(
    (const __attribute__((address_space(1))) void*)g,
    (__attribute__((address_space(3))) void*)l, 16, 0, 0);
}

// ---- fused: gates = softmax(x@Wg+bg); A'[n][e*1024+k] = bf16(g_e * x[n,k]);
//      A'[n][8192+c] = gate bf16 (c<8) else 0.  One wave per token. ----
__global__ void k_gab(const float* __restrict__ x, const float* __restrict__ Wg,
                      const float* __restrict__ bg, u16* __restrict__ Ap){
  int lane = threadIdx.x & 63;
  int n = blockIdx.x*4 + (threadIdx.x>>6);
  const float* xr = x + (size_t)n*IN_DIM;
  // lane owns k = lane*8..+7 and 512+lane*8..+7
  float4 xl0 = *(const float4*)(xr + lane*8);
  float4 xl1 = *(const float4*)(xr + lane*8 + 4);
  float4 xh0 = *(const float4*)(xr + 512 + lane*8);
  float4 xh1 = *(const float4*)(xr + 512 + lane*8 + 4);
  float p[NE];
  #pragma unroll
  for(int e=0;e<NE;e++) p[e]=0.f;
  const float* wl = Wg + (size_t)(lane*8)*NE;
  const float* wh = Wg + (size_t)(512 + lane*8)*NE;
  #pragma unroll
  for(int j=0;j<8;j++){
    float xa = (&xl0.x)[j&3], xb_ = (&xh0.x)[j&3];
    if (j>=4){ xa = (&xl1.x)[j&3]; xb_ = (&xh1.x)[j&3]; }
    int jj = (j>=4) ? j : j;   // j indexes element; rows interleaved below
    #pragma unroll
    for(int e=0;e<NE;e++){
      p[e] = fmaf(xa, wl[(size_t)jj*NE+e], p[e]);
      p[e] = fmaf(xb_, wh[(size_t)jj*NE+e], p[e]);
    }
  }
  #pragma unroll
  for(int e=0;e<NE;e++){
    float v = p[e];
    #pragma unroll
    for(int off=32;off;off>>=1) v += __shfl_xor(v, off);
    p[e]=v;
  }
  float m = -1e30f;
  #pragma unroll
  for(int e=0;e<NE;e++){ p[e] += bg[e]; m = fmaxf(m, p[e]); }
  float s = 0.f;
  #pragma unroll
  for(int e=0;e<NE;e++){ p[e] = __expf(p[e]-m); s += p[e]; }
  float inv = 1.f/s;
  #pragma unroll
  for(int e=0;e<NE;e++) p[e] *= inv;       // all lanes hold full gate vector
  u16* arow = Ap + (size_t)n*KTOT;
  #pragma unroll
  for(int e=0;e<NE;e++){
    float ge = p[e];
    union { u16 u[8]; short8 v; } lo, hi;
    #pragma unroll
    for(int j=0;j<4;j++){
      lo.u[j]   = f2bf(ge*(&xl0.x)[j]);  lo.u[j+4] = f2bf(ge*(&xl1.x)[j]);
      hi.u[j]   = f2bf(ge*(&xh0.x)[j]);  hi.u[j+4] = f2bf(ge*(&xh1.x)[j]);
    }
    *(short8*)(arow + (size_t)e*IN_DIM + lane*8)       = lo.v;
    *(short8*)(arow + (size_t)e*IN_DIM + 512 + lane*8) = hi.v;
  }
  arow[KE + lane] = (lane < NE) ? f2bf(p[lane]) : (u16)0;
}

// ---- We [8192k][1024o] fp32 -> WeT bf16 [1024o][8256k]; kb==127 blocks
//      also write the bias tail cols 8192..8255 (be or 0). ----
__global__ void k_wetT(const float* __restrict__ We, const float* __restrict__ be,
                       u16* __restrict__ WeT){
  __shared__ float tile[64][65];
  int kb = blockIdx.x & 127;
  int ob = blockIdx.x >> 7;
  int k0 = kb*64, o0 = ob*64;
  int tr = threadIdx.x >> 4;
  int tc = (threadIdx.x & 15) * 4;
  #pragma unroll
  for (int p=0;p<4;p++){
    int r = p*16 + tr;
    float4 v = *(const float4*)(We + (size_t)(k0+r)*OUT_DIM + o0 + tc);
    tile[r][tc+0]=v.x; tile[r][tc+1]=v.y; tile[r][tc+2]=v.z; tile[r][tc+3]=v.w;
  }
  __syncthreads();
  #pragma unroll
  for (int p=0;p<4;p++){
    int r = p*16 + tr;              // o_local
    ushort4 o;
    o.x = f2bf(tile[tc+0][r]);
    o.y = f2bf(tile[tc+1][r]);
    o.z = f2bf(tile[tc+2][r]);
    o.w = f2bf(tile[tc+3][r]);
    *(ushort4*)(WeT + (size_t)(o0+r)*KTOT + k0 + tc) = o;
  }
  if (kb == 127){
    int tr2 = threadIdx.x >> 2;          // 0..63
    int tc2 = (threadIdx.x & 3) * 16;    // 0,16,32,48
    int o = o0 + tr2;
    #pragma unroll
    for (int c2=0;c2<16;c2++){
      int c = tc2 + c2;
      WeT[(size_t)o*KTOT + KE + c] = (c < NE) ? f2bf(be[(size_t)c*OUT_DIM + o]) : (u16)0;
    }
  }
}

// ---- GEMM: C[8192x1024] = A'[8192x8256] @ WeT^T ----
// BM=256,BN=128,BK=64, 512 thr (8 waves 4Mx2N, 64x64/wave), triple-buffer LDS,
// 2 phases/K-tile {8 ds_read, 3 gload issue, barrier, 16 MFMA, barrier},
// counted vmcnt(6) once per tile BEFORE the tile's final barrier (T3+T4),
// XOR-swizzled LDS (T2: linear dest + inverse-swz source + swz ds_read),
// setprio around MFMA (T5), XCD bm-chunk swizzle (T1).
__global__ __launch_bounds__(512,2) void k_gemm(const u16* __restrict__ Ap,
      const u16* __restrict__ Wt, float* __restrict__ C){
  __shared__ u16 sA[3][BM*BK];   // 3 x 32KB
  __shared__ u16 sB[3][BN*BK];   // 3 x 16KB   total 144KB
  int tid = threadIdx.x;
  int wave = tid>>6, lane = tid&63;
  // XCD chunking: 256 blocks, xcd = bid&7 owns bm in [4*xcd,4*xcd+4) x all bn
  int g = (blockIdx.x & 7)*32 + (blockIdx.x >> 3);
  int bm = g >> 3;        // 0..31
  int bn = g & 7;         // 0..7
  int wr = wave>>1, wc = wave&1;     // 4M x 2N

  // staging decomposition: 512 thr x 16B; A tile 32KB = 4 shots, B 16KB = 2
  int r8 = tid>>3, gl = tid&7;
  const u16* pA[4]; const u16* pB[2];
  int ldsA[4], ldsB[2];
  #pragma unroll
  for (int q=0;q<4;q++){
    int r = q*64 + r8;
    pA[q] = Ap + (size_t)(bm*BM + r)*KTOT + ((gl ^ (r&7))<<3);
    ldsA[q] = r*BK + gl*8;           // linear dest (wave-contiguous)
  }
  #pragma unroll
  for (int q=0;q<2;q++){
    int r = q*64 + r8;
    pB[q] = Wt + (size_t)(bn*BN + r)*KTOT + ((gl ^ (r&7))<<3);
    ldsB[q] = r*BK + gl*8;
  }

  f32x4 acc[4][4];
  #pragma unroll
  for(int m=0;m<4;m++)
    #pragma unroll
    for(int n=0;n<4;n++)
      acc[m][n] = (f32x4){0.f,0.f,0.f,0.f};

  int rA0 = wr*64 + (lane&15);
  int rB0 = wc*64 + (lane&15);
  int krow = lane>>4;

  // prologue: stage tiles 0 and 1 (12 loads outstanding)
  #pragma unroll
  for (int q=0;q<4;q++){ gload16(pA[q], &sA[0][ldsA[q]]); pA[q] += BK; }
  #pragma unroll
  for (int q=0;q<2;q++){ gload16(pB[q], &sB[0][ldsB[q]]); pB[q] += BK; }
  #pragma unroll
  for (int q=0;q<4;q++){ gload16(pA[q], &sA[1][ldsA[q]]); pA[q] += BK; }
  #pragma unroll
  for (int q=0;q<2;q++){ gload16(pB[q], &sB[1][ldsB[q]]); pB[q] += BK; }
  asm volatile("s_waitcnt vmcnt(6)" ::: "memory");   // tile 0 landed
  __builtin_amdgcn_s_barrier();

  int cur = 0;
  for (int t=0; t<NKT; ++t){
    int nb = (cur==2) ? 0 : cur+1;
    int stage = (cur==0) ? 2 : cur-1;   // (t+2)%3
    const u16* sa = sA[cur];
    const u16* sb = sB[cur];
    #pragma unroll
    for (int ph=0; ph<2; ++ph){
      int kk = ph*32;
      short8 af[4], bfr[4];
      int g0 = (kk>>3) + krow;
      #pragma unroll
      for (int m=0;m<4;m++){
        int R = rA0 + m*16;
        af[m] = *(const short8*)(sa + R*BK + ((g0 ^ (R&7))<<3));
      }
      #pragma unroll
      for (int n=0;n<4;n++){
        int R = rB0 + n*16;
        bfr[n] = *(const short8*)(sb + R*BK + ((g0 ^ (R&7))<<3));
      }
      if (t+2 < NKT){
        if (ph==0){
          gload16(pA[0], &sA[stage][ldsA[0]]); pA[0] += BK;
          gload16(pA[1], &sA[stage][ldsA[1]]); pA[1] += BK;
          gload16(pB[0], &sB[stage][ldsB[0]]); pB[0] += BK;
        } else {
          gload16(pA[2], &sA[stage][ldsA[2]]); pA[2] += BK;
          gload16(pA[3], &sA[stage][ldsA[3]]); pA[3] += BK;
          gload16(pB[1], &sB[stage][ldsB[1]]); pB[1] += BK;
        }
      }
      __builtin_amdgcn_s_barrier();
      __builtin_amdgcn_s_setprio(1);
      #pragma unroll
      for (int m=0;m<4;m++)
        #pragma unroll
        for (int n=0;n<4;n++)
          acc[m][n] = __builtin_amdgcn_mfma_f32_16x16x32_bf16(af[m], bfr[n], acc[m][n], 0,0,0);
      __builtin_amdgcn_s_setprio(0);
      if (ph==0){
        __builtin_amdgcn_s_barrier();
      } else {
        // publish next tile's stage before anyone reads it:
        // outstanding = S(t+1){6} + S(t+2){6 if issued}; drain S(t+1).
        if (t <= NKT-3) asm volatile("s_waitcnt vmcnt(6)" ::: "memory");
        else            asm volatile("s_waitcnt vmcnt(0)" ::: "memory");
        __builtin_amdgcn_s_barrier();
      }
    }
    cur = nb;
  }

  // epilogue: C/D layout col=lane&15, row=(lane>>4)*4+reg
  int row0 = bm*BM + wr*64 + (lane>>4)*4;
  int col0 = bn*BN + wc*64 + (lane&15);
  #pragma unroll
  for (int m=0;m<4;m++)
    #pragma unroll
    for (int n=0;n<4;n++)
      #pragma unroll
      for (int j=0;j<4;j++)
        C[(size_t)(row0 + m*16 + j)*OUT_DIM + col0 + n*16] = acc[m][n][j];
}

extern "C" void kernel_launch(void* const* d_in, const int* in_sizes, int n_in,
                              void* d_out, int out_size, void* d_ws, size_t ws_size,
                              hipStream_t stream){
  const float* x  = (const float*)d_in[0];
  const float* We = (const float*)d_in[1];
  const float* be = (const float*)d_in[2];
  const float* Wg = (const float*)d_in[3];
  const float* bg = (const float*)d_in[4];
  float* out = (float*)d_out;
  char* ws = (char*)d_ws;
  // ws: A' bf16 [8192][8256] 135.3MB | WeT bf16 [1024][8256] 16.9MB
  u16* Ap  = (u16*)ws;
  u16* WeT = (u16*)(ws + (size_t)NT*KTOT*2);

  k_gab <<<NT/4, 256, 0, stream>>>(x, Wg, bg, Ap);
  k_wetT<<<(KE/64)*(OUT_DIM/64), 256, 0, stream>>>(We, be, WeT);
  k_gemm<<<(NT/BM)*(OUT_DIM/BN), 512, 0, stream>>>(Ap, WeT, out);
}